// Round 1
// baseline (322.125 us; speedup 1.0000x reference)
//
#include <hip/hip_runtime.h>

// FSUConv2d stochastic-computing conv — latency-optimized restructure.
// N=8, C=32, H=W=16, OC=64, K=3, PAD=1, RLEN=256, CKK=288, B=2048.
//
// out[n,o,h,w] = sum_k [ x_k ? (w_bin[o,k] > rev8(i1)) : !(w_bin[o,k] > rev8(i0)) ]
//               + (b_bin[o] > rev8(brdx[o]))
//
// Key identities used:
//  * rng[idx % 256] == bitrev8(idx) == __brev(idx) >> 24 (computed in-register).
//  * float compare (w > rev) with integral w in [0,256], rev in [0,255]:
//      sat(w<<24) > __brev(idx)   as u32   (w==256 -> 0xFFFFFFFF, always true)
//    -> only w needs preprocessing (4 values/row), indices compare raw brev.
//  * per-element result is ONE BIT -> reduce over the 64-lane wave with
//    __ballot + __popcll (SALU) instead of a 6-step dependent shfl chain.
//
// Structure: grid = 2048 blocks (one per patch b), 256 threads = 4 waves.
// Unfold + bias bits once per block. Wave w streams 16 rows o = w*16+j with
// an A/B double-buffered prefetch so the next row's 3 global vector loads are
// in flight while the current row computes (latency hiding, Little's law).

#define CH   32
#define HH   16
#define WW   16
#define OCN  64
#define CKK  288
#define LL   256     // H*W
#define BB   2048    // N*H*W

__device__ __forceinline__ float sobol_val(int idx) {
    // idx guaranteed in [0, 256) by setup (randint(0, RLEN))
    return (float)(__brev((unsigned)idx) >> 24);
}

// Comparison key: (w > bitrev8(i))  <=>  wkey(w) > __brev(i)  (unsigned).
// w_bin is an integral float in [0,256]; 256 must win every compare.
__device__ __forceinline__ unsigned wkey(float wv) {
    unsigned wi = (unsigned)wv;
    return (wi >= 256u) ? 0xFFFFFFFFu : (wi << 24);
}

struct RowBuf {
    int4   a, c;     // wrdx1 / wrdx0, k = lane*4 .. lane*4+3
    float4 wv;       // w_bin row, same k
    int4   at, ct;   // tail k = 256+lane*4 .. (valid in lanes 0..7, else 0)
    float4 wt;
};

__global__ __launch_bounds__(256, 4) void fsuconv_kernel(
    const float* __restrict__ x,       // [8,32,16,16] bits
    const float* __restrict__ w_bin,   // [64,288]
    const float* __restrict__ b_bin,   // [64]
    const int*   __restrict__ wrdx1,   // [2048,64,288]
    const int*   __restrict__ wrdx0,   // [2048,64,288]
    const int*   __restrict__ brdx,    // [64]
    float*       __restrict__ out)     // [8,64,16,16]
{
    __shared__ __align__(16) float ib1[CKK];
    __shared__ float bbit[OCN];

    const int b  = blockIdx.x;         // patch index in [0, 2048)
    const int n  = b >> 8;
    const int l  = b & 255;
    const int h  = l >> 4;
    const int w0 = l & 15;

    // Phase 1: unfold x-row for this patch into LDS (once per patch now,
    // was 16x redundant before).
    for (int k = threadIdx.x; k < CKK; k += 256) {
        int c  = k / 9;
        int r  = k - c * 9;
        int kh = r / 3;
        int kw = r - kh * 3;
        int ih = h + kh - 1;
        int iw = w0 + kw - 1;
        float v = 0.f;
        if ((unsigned)ih < 16u && (unsigned)iw < 16u)
            v = x[((n * CH + c) * HH + ih) * WW + iw];
        ib1[k] = v;
    }
    // Bias bits once per block.
    if (threadIdx.x < OCN) {
        int o = threadIdx.x;
        bbit[o] = (b_bin[o] > sobol_val(brdx[o])) ? 1.f : 0.f;
    }
    __syncthreads();

    const int wave = threadIdx.x >> 6;
    const int lane = threadIdx.x & 63;

    // Per-wave x masks (64-bit, one bit per lane, per element slot e=0..3).
    // Same for every row of this patch -> computed once.
    float4 xv  = ((const float4*)ib1)[lane];
    float4 xtv = make_float4(0.f, 0.f, 0.f, 0.f);
    if (lane < 8) xtv = ((const float4*)ib1)[64 + lane];

    const unsigned long long xm0 = __ballot(xv.x != 0.f);
    const unsigned long long xm1 = __ballot(xv.y != 0.f);
    const unsigned long long xm2 = __ballot(xv.z != 0.f);
    const unsigned long long xm3 = __ballot(xv.w != 0.f);
    const unsigned long long xt0 = __ballot(xtv.x != 0.f);  // bits 8..63 = 0
    const unsigned long long xt1 = __ballot(xtv.y != 0.f);
    const unsigned long long xt2 = __ballot(xtv.z != 0.f);
    const unsigned long long xt3 = __ballot(xtv.w != 0.f);

    // This wave owns rows o = obase .. obase+15.
    const int obase = wave * 16;
    const int*   p1 = wrdx1 + ((size_t)b * OCN + obase) * CKK;
    const int*   p0 = wrdx0 + ((size_t)b * OCN + obase) * CKK;
    const float* pw = w_bin + (size_t)obase * CKK;

    RowBuf A = {}, B = {};   // zero-init so lanes>=8 tail regs are benign

    auto loadrow = [&](RowBuf& rb, int j) {
        const int4*   q1 = (const int4*)(p1 + j * CKK);
        const int4*   q0 = (const int4*)(p0 + j * CKK);
        const float4* qw = (const float4*)(pw + j * CKK);
        rb.a  = q1[lane];
        rb.c  = q0[lane];
        rb.wv = qw[lane];
        if (lane < 8) {                 // tail k in [256,288): 8 int4 chunks
            rb.at = q1[64 + lane];
            rb.ct = q0[64 + lane];
            rb.wt = qw[64 + lane];
        }
    };

    // One 64-element chunk: bit = x ? (w > rev(i1)) : !(w > rev(i0)),
    // assembled as a 64-bit wave mask (VOP3 v_cmp -> SGPR pair, SALU combine).
    auto chunk = [&](float wf, int a1, int a0,
                     unsigned long long xm) -> unsigned long long {
        unsigned k = wkey(wf);
        unsigned long long m1 = __ballot(k > __brev((unsigned)a1));
        unsigned long long m0 = __ballot(k > __brev((unsigned)a0));
        return (xm & m1) | (~xm & ~m0);
    };

    auto computerow = [&](const RowBuf& rb, int j) {
        unsigned cnt = 0;
        cnt += __popcll(chunk(rb.wv.x, rb.a.x, rb.c.x, xm0));
        cnt += __popcll(chunk(rb.wv.y, rb.a.y, rb.c.y, xm1));
        cnt += __popcll(chunk(rb.wv.z, rb.a.z, rb.c.z, xm2));
        cnt += __popcll(chunk(rb.wv.w, rb.a.w, rb.c.w, xm3));
        // tail: only bits 0..7 are meaningful (lanes >=8 hold garbage/zero)
        cnt += __popcll(chunk(rb.wt.x, rb.at.x, rb.ct.x, xt0) & 0xFFull);
        cnt += __popcll(chunk(rb.wt.y, rb.at.y, rb.ct.y, xt1) & 0xFFull);
        cnt += __popcll(chunk(rb.wt.z, rb.at.z, rb.ct.z, xt2) & 0xFFull);
        cnt += __popcll(chunk(rb.wt.w, rb.at.w, rb.ct.w, xt3) & 0xFFull);
        if (lane == 0) {
            int o = obase + j;
            out[((size_t)n * OCN + o) * LL + l] = (float)cnt + bbit[o];
        }
    };

    // Software-pipelined: row j+1's loads are issued before row j's compute
    // forces its s_waitcnt -> one row of prefetch always in flight.
    loadrow(A, 0);
    #pragma unroll
    for (int j = 0; j < 16; j += 2) {
        loadrow(B, j + 1);
        computerow(A, j);
        if (j + 2 < 16) loadrow(A, j + 2);
        computerow(B, j + 1);
    }
}

extern "C" void kernel_launch(void* const* d_in, const int* in_sizes, int n_in,
                              void* d_out, int out_size, void* d_ws, size_t ws_size,
                              hipStream_t stream) {
    const float* x     = (const float*)d_in[0];
    const float* w_bin = (const float*)d_in[1];
    const float* b_bin = (const float*)d_in[2];
    // d_in[3] = rng — replaced by closed-form bit-reversal (see sobol_val)
    const int*   wrdx1 = (const int*)d_in[4];
    const int*   wrdx0 = (const int*)d_in[5];
    const int*   brdx  = (const int*)d_in[6];
    float*       out   = (float*)d_out;

    // one block per patch b; wave w handles o = w*16 .. w*16+15
    dim3 grid(BB);
    dim3 block(256);
    fsuconv_kernel<<<grid, block, 0, stream>>>(x, w_bin, b_bin, wrdx1, wrdx0, brdx, out);
}